// Round 2
// baseline (3811.514 us; speedup 1.0000x reference)
//
#include <hip/hip_runtime.h>
#include <cstddef>
#include <cstdint>

// Problem constants (B=2, S=2048, E=1024, H=16, D=64)
#define BATCH 2
#define S_LEN 2048
#define E_DIM 1024
#define NH    16
#define HD    64
#define M_ROWS (BATCH * S_LEN)   // 4096

// ---------------------------------------------------------------------------
// GEMM (NT): C[m,n] = sum_k A[m,k] * B[n,k] + bias[n]   (fp32, unchanged)
// ---------------------------------------------------------------------------
#define GBM 128
#define GBN 128
#define GBK 8

__global__ __launch_bounds__(256)
void gemm_nt(const float* __restrict__ A, const float* __restrict__ B,
             const float* __restrict__ bias, float* __restrict__ C,
             int M, int N, int K)
{
    __shared__ float As[GBK][GBM + 4];
    __shared__ float Bs[GBK][GBN + 4];
    const int tid = threadIdx.x;
    const int tx  = tid & 15;
    const int ty  = tid >> 4;
    const int m0  = blockIdx.x * GBM;
    const int n0  = blockIdx.y * GBN;
    const int lrow = tid >> 1;
    const int lcol = (tid & 1) * 4;

    float acc[8][8];
#pragma unroll
    for (int i = 0; i < 8; ++i)
#pragma unroll
        for (int j = 0; j < 8; ++j) acc[i][j] = 0.f;

    for (int kb = 0; kb < K; kb += GBK) {
        const float4 a4 = *(const float4*)(A + (size_t)(m0 + lrow) * K + kb + lcol);
        const float4 b4 = *(const float4*)(B + (size_t)(n0 + lrow) * K + kb + lcol);
        __syncthreads();
        As[lcol + 0][lrow] = a4.x; As[lcol + 1][lrow] = a4.y;
        As[lcol + 2][lrow] = a4.z; As[lcol + 3][lrow] = a4.w;
        Bs[lcol + 0][lrow] = b4.x; Bs[lcol + 1][lrow] = b4.y;
        Bs[lcol + 2][lrow] = b4.z; Bs[lcol + 3][lrow] = b4.w;
        __syncthreads();
#pragma unroll
        for (int kk = 0; kk < GBK; ++kk) {
            float a[8], b[8];
#pragma unroll
            for (int i = 0; i < 8; ++i) a[i] = As[kk][ty + 16 * i];
#pragma unroll
            for (int j = 0; j < 8; ++j) b[j] = Bs[kk][tx + 16 * j];
#pragma unroll
            for (int i = 0; i < 8; ++i)
#pragma unroll
                for (int j = 0; j < 8; ++j) acc[i][j] += a[i] * b[j];
        }
    }

#pragma unroll
    for (int i = 0; i < 8; ++i) {
        const size_t m = (size_t)(m0 + ty + 16 * i);
#pragma unroll
        for (int j = 0; j < 8; ++j) {
            const int n = n0 + tx + 16 * j;
            C[m * N + n] = acc[i][j] + bias[n];
        }
    }
}

// ---------------------------------------------------------------------------
// Attention v2 — softmax over HEADS is local per (b,q,k), so stream keys.
//
// Thread (qi = tid>>4, h = tid&15):
//   - Qreg[64]: Q[b][q0+qi][h*64..h*64+63], loaded once (registers)
//   - Oacc[64]: running sum_k w * V[k][h*64+d]       (registers)
// Per key kj: sc = dot64(Qreg, Ks[kj][h]); softmax over the 16 h-lanes
// via __shfl_xor (1,2,4,8); Oacc += w * Vs[kj][h].
//
// K/V staged per 8-key chunk in LDS, layout [kj][h*68 + d] (pad 64->68:
// read banks = 4h mod 32 -> only h vs h+8 alias = 2-way = free).
// KSPLIT=2 over keys: grid = B*(S/TQ)*2 = 512 blocks -> 2 blocks/CU,
// 8 waves/CU. Epilogue: fp32 unsafeAtomicAdd into zeroed ctx.
// LDS: 2 * 8 * 1088 * 4B = 69632 B  (2 blocks/CU at 160 KB).
// ---------------------------------------------------------------------------
#define TQ      16
#define KC      8            // keys per LDS chunk
#define HSEG    68           // padded head-segment stride (floats)
#define KROW    (NH * HSEG)  // 1088 floats per staged key row
#define KSPLIT  2

__global__ __launch_bounds__(256, 2)
void attn_v2(const float* __restrict__ q, const float* __restrict__ k,
             const float* __restrict__ v, float* __restrict__ ctx)
{
    __shared__ float Ks[KC * KROW];
    __shared__ float Vs[KC * KROW];

    const int tid   = threadIdx.x;
    const int h     = tid & 15;
    const int qi    = tid >> 4;
    const int bid   = blockIdx.x;
    const int khalf = bid & (KSPLIT - 1);
    const int qt    = (bid >> 1) & 127;          // 128 q-tiles per batch
    const int b     = bid >> 8;                  // 0..1
    const int q0    = qt * TQ;

    // ---- load Q segment into registers (once) ----
    float qreg[64];
    {
        const size_t qb = ((size_t)b * S_LEN + q0 + qi) * E_DIM + h * HD;
#pragma unroll
        for (int d4 = 0; d4 < 16; ++d4)
            *(float4*)&qreg[d4 * 4] = *(const float4*)(q + qb + d4 * 4);
    }

    float oacc[64];
#pragma unroll
    for (int j = 0; j < 64; ++j) oacc[j] = 0.f;

    const int   kspan = S_LEN / KSPLIT;          // 1024 keys per block
    const int   kbeg  = khalf * kspan;
    const size_t kmat = (size_t)b * S_LEN * E_DIM;

    for (int kt = 0; kt < kspan; kt += KC) {
        const size_t gkb = kmat + (size_t)(kbeg + kt) * E_DIM;
        __syncthreads();                          // previous chunk's reads done
        // stage KC=8 rows of K and V (8 float4 each per thread, coalesced)
#pragma unroll
        for (int u = 0; u < KC; ++u) {
            const int c = tid;                    // float4 col 0..255
            const float4 kv = *(const float4*)(k + gkb + (size_t)u * E_DIM + c * 4);
            const float4 vv = *(const float4*)(v + gkb + (size_t)u * E_DIM + c * 4);
            const int slot = u * KROW + (c >> 4) * HSEG + (c & 15) * 4;
            *(float4*)&Ks[slot] = kv;
            *(float4*)&Vs[slot] = vv;
        }
        __syncthreads();

#pragma unroll
        for (int kj = 0; kj < KC; ++kj) {
            const int base = kj * KROW + h * HSEG;
            // score: dot64 in registers (same-h lanes broadcast from LDS)
            float s0 = 0.f, s1 = 0.f, s2 = 0.f, s3 = 0.f;
#pragma unroll
            for (int d4 = 0; d4 < 16; ++d4) {
                const float4 kv = *(const float4*)&Ks[base + d4 * 4];
                s0 += qreg[d4 * 4 + 0] * kv.x;
                s1 += qreg[d4 * 4 + 1] * kv.y;
                s2 += qreg[d4 * 4 + 2] * kv.z;
                s3 += qreg[d4 * 4 + 3] * kv.w;
            }
            float sc = (s0 + s1) + (s2 + s3);
            // softmax over heads = 16-lane butterfly (lanes qi*16+h)
            float mx = sc;
            mx = fmaxf(mx, __shfl_xor(mx, 1));
            mx = fmaxf(mx, __shfl_xor(mx, 2));
            mx = fmaxf(mx, __shfl_xor(mx, 4));
            mx = fmaxf(mx, __shfl_xor(mx, 8));
            float e = __expf((sc - mx) * 0.125f);   // 1/sqrt(64)
            float sm = e;
            sm += __shfl_xor(sm, 1);
            sm += __shfl_xor(sm, 2);
            sm += __shfl_xor(sm, 4);
            sm += __shfl_xor(sm, 8);
            const float w = e * __builtin_amdgcn_rcpf(sm);
            // PV: Oacc += w * V[kj][h][:]
#pragma unroll
            for (int d4 = 0; d4 < 16; ++d4) {
                const float4 vv = *(const float4*)&Vs[base + d4 * 4];
                oacc[d4 * 4 + 0] += w * vv.x;
                oacc[d4 * 4 + 1] += w * vv.y;
                oacc[d4 * 4 + 2] += w * vv.z;
                oacc[d4 * 4 + 3] += w * vv.w;
            }
        }
    }

    // ---- epilogue: atomic accumulate the k-half partial into ctx ----
    const size_t ob = ((size_t)b * S_LEN + q0 + qi) * E_DIM + h * HD;
#pragma unroll
    for (int j = 0; j < 64; ++j)
        unsafeAtomicAdd(ctx + ob + j, oacc[j]);
}

// ---------------------------------------------------------------------------
extern "C" void kernel_launch(void* const* d_in, const int* in_sizes, int n_in,
                              void* d_out, int out_size, void* d_ws, size_t ws_size,
                              hipStream_t stream)
{
    const float* x  = (const float*)d_in[0];
    const float* Wq = (const float*)d_in[1];
    const float* bq = (const float*)d_in[2];
    const float* Wk = (const float*)d_in[3];
    const float* bk = (const float*)d_in[4];
    const float* Wv = (const float*)d_in[5];
    const float* bv = (const float*)d_in[6];
    const float* Wo = (const float*)d_in[7];
    const float* bo = (const float*)d_in[8];
    float* out = (float*)d_out;

    // workspace layout (fp32): q | k | v | ctx  (16 MB each, 64 MB total)
    const size_t MAT = (size_t)M_ROWS * E_DIM;
    float* qb  = (float*)d_ws;
    float* kb2 = qb + MAT;
    float* vb  = kb2 + MAT;
    float* cb  = vb + MAT;

    dim3 ggrid(M_ROWS / GBM, E_DIM / GBN);   // 32 x 8 = 256 blocks
    gemm_nt<<<ggrid, 256, 0, stream>>>(x, Wq, bq, qb,  M_ROWS, E_DIM, E_DIM);
    gemm_nt<<<ggrid, 256, 0, stream>>>(x, Wk, bk, kb2, M_ROWS, E_DIM, E_DIM);
    gemm_nt<<<ggrid, 256, 0, stream>>>(x, Wv, bv, vb,  M_ROWS, E_DIM, E_DIM);

    hipMemsetAsync(cb, 0, MAT * sizeof(float), stream);   // ctx zero (atomics)

    attn_v2<<<BATCH * (S_LEN / TQ) * KSPLIT, 256, 0, stream>>>(qb, kb2, vb, cb);

    gemm_nt<<<ggrid, 256, 0, stream>>>(cb, Wo, bo, out, M_ROWS, E_DIM, E_DIM);
}

// Round 3
// 479.609 us; speedup vs baseline: 7.9471x; 7.9471x over previous
//
#include <hip/hip_runtime.h>
#include <cstddef>
#include <cstdint>

// Problem: B=2, S=2048, E=1024, H=16, D=64.  Softmax over HEADS (ref quirk).
#define BATCH 2
#define S_LEN 2048
#define E_DIM 1024
#define NH    16
#define HD    64
#define M_ROWS (BATCH * S_LEN)   // 4096

typedef unsigned short u16;
typedef short  bf16x8 __attribute__((ext_vector_type(8)));
typedef float  f32x4  __attribute__((ext_vector_type(4)));

__device__ __forceinline__ u16 f2bf(float f) {
    union { float f; unsigned u; } v; v.f = f;
    unsigned r = v.u + 0x7fffu + ((v.u >> 16) & 1u);   // RNE
    return (u16)(r >> 16);
}
__device__ __forceinline__ float bf2f(u16 h) {
    union { unsigned u; float f; } v; v.u = ((unsigned)h) << 16;
    return v.f;
}

// ---------------------------------------------------------------------------
// fp32 -> bf16 bulk convert (n % 4 == 0)
// ---------------------------------------------------------------------------
__global__ void cvt_bf16(const float* __restrict__ in, u16* __restrict__ out, int n)
{
    int i = (blockIdx.x * 256 + threadIdx.x) * 4;
    if (i + 3 < n) {
        float4 v = *(const float4*)(in + i);
        u16 o[4] = { f2bf(v.x), f2bf(v.y), f2bf(v.z), f2bf(v.w) };
        *(uint2*)(out + i) = *(const uint2*)o;
    }
}

// ---------------------------------------------------------------------------
// ctx = ctxA + ctxB  (bf16 in/out, fp32 add)
// ---------------------------------------------------------------------------
__global__ void combine_ctx(const u16* __restrict__ a, const u16* __restrict__ b,
                            u16* __restrict__ c, int n)
{
    int i = (blockIdx.x * 256 + threadIdx.x) * 4;
    if (i + 3 < n) {
        uint2 ua = *(const uint2*)(a + i);
        uint2 ub = *(const uint2*)(b + i);
        const u16* pa = (const u16*)&ua; const u16* pb = (const u16*)&ub;
        u16 o[4];
#pragma unroll
        for (int j = 0; j < 4; ++j) o[j] = f2bf(bf2f(pa[j]) + bf2f(pb[j]));
        *(uint2*)(c + i) = *(const uint2*)o;
    }
}

// ---------------------------------------------------------------------------
// V [b][s][e] -> Vt [b][e][s]   (bf16). grid = 2*128 blocks, 256 thr.
// ---------------------------------------------------------------------------
__global__ void transpose_v(const u16* __restrict__ Vb, u16* __restrict__ Vt)
{
    const int t  = threadIdx.x;
    const int b  = blockIdx.x >> 7;
    const int s0 = (blockIdx.x & 127) * 16;
    const int s  = t >> 4;          // 0..15
    const int eq = t & 15;          // 0..15
    const size_t inb  = ((size_t)b * S_LEN + s0 + s) * E_DIM;
    const size_t outb = (size_t)b * E_DIM * S_LEN;
#pragma unroll
    for (int i = 0; i < 8; ++i) {
        const int e8 = i * 16 + eq;                        // 0..127
        bf16x8 v = *(const bf16x8*)(Vb + inb + e8 * 8);
        const u16* pv = (const u16*)&v;
#pragma unroll
        for (int j = 0; j < 8; ++j)
            Vt[outb + (size_t)(e8 * 8 + j) * S_LEN + s0 + s] = pv[j];
    }
}

// ---------------------------------------------------------------------------
// bf16 MFMA GEMM (NT): C[m,n] = sum_k A[m,k]*B[n,k] + bias[n]
// 128x128 tile, BK=32, 256 thr (4 waves, 2x2), 4x4 MFMA 16x16x32 acc / wave.
// ---------------------------------------------------------------------------
template<bool OUT_BF16>
__global__ __launch_bounds__(256, 2)
void gemm_bt(const u16* __restrict__ A, const u16* __restrict__ B,
             const float* __restrict__ bias, void* __restrict__ Cout,
             int M, int N, int K)
{
    __shared__ u16 Al[128 * 32];
    __shared__ u16 Bl[128 * 32];
    const int t    = threadIdx.x;
    const int w    = t >> 6, lane = t & 63;
    const int quad = lane >> 4, lm = lane & 15;
    const int wy   = w >> 1, wx = w & 1;
    const int m0   = blockIdx.x * 128, n0 = blockIdx.y * 128;

    f32x4 acc[4][4] = {};

    for (int kb = 0; kb < K; kb += 32) {
        bf16x8 av[2], bv[2];
#pragma unroll
        for (int i = 0; i < 2; ++i) {
            const int unit = i * 256 + t;
            const int r = unit >> 2, cu = unit & 3;
            av[i] = *(const bf16x8*)(A + (size_t)(m0 + r) * K + kb + cu * 8);
            bv[i] = *(const bf16x8*)(B + (size_t)(n0 + r) * K + kb + cu * 8);
        }
        __syncthreads();
#pragma unroll
        for (int i = 0; i < 2; ++i) {
            const int unit = i * 256 + t;
            const int r = unit >> 2, cu = unit & 3;
            *(bf16x8*)(Al + r * 32 + cu * 8) = av[i];
            *(bf16x8*)(Bl + r * 32 + cu * 8) = bv[i];
        }
        __syncthreads();

        bf16x8 af[4], bfr[4];
#pragma unroll
        for (int i = 0; i < 4; ++i)
            af[i] = *(const bf16x8*)(Al + (wy * 64 + i * 16 + lm) * 32 + quad * 8);
#pragma unroll
        for (int j = 0; j < 4; ++j)
            bfr[j] = *(const bf16x8*)(Bl + (wx * 64 + j * 16 + lm) * 32 + quad * 8);
#pragma unroll
        for (int i = 0; i < 4; ++i)
#pragma unroll
            for (int j = 0; j < 4; ++j)
                acc[i][j] = __builtin_amdgcn_mfma_f32_16x16x32_bf16(af[i], bfr[j], acc[i][j], 0, 0, 0);
    }

#pragma unroll
    for (int j = 0; j < 4; ++j) {
        const int n = n0 + wx * 64 + j * 16 + lm;
        const float bs = bias[n];
#pragma unroll
        for (int i = 0; i < 4; ++i) {
            const int mrow = m0 + wy * 64 + i * 16 + quad * 4;
#pragma unroll
            for (int rg = 0; rg < 4; ++rg) {
                const float val = acc[i][j][rg] + bs;
                if (OUT_BF16) ((u16*)Cout)[(size_t)(mrow + rg) * N + n] = f2bf(val);
                else          ((float*)Cout)[(size_t)(mrow + rg) * N + n] = val;
            }
        }
    }
}

// ---------------------------------------------------------------------------
// MFMA attention, softmax over heads.
// Block = 256 thr (4 waves); wave w owns heads 4w..4w+3. Q-tile = 16 rows.
// Grid = B * 128 qtiles * KSPLIT(2) = 512 blocks.
// Per 32-key chunk: QK via mfma_16x16x32 (K direct from global/L2),
//   S[h][q][k] fp32 in LDS -> wide softmax over h -> P[h][q][k] bf16 ->
//   PV via mfma with pre-transposed Vt (direct from global/L2).
// LDS: S 32 KB + P 16 KB = 48 KB.
// ---------------------------------------------------------------------------
__global__ __launch_bounds__(256, 2)
void attn_v3(const u16* __restrict__ Q, const u16* __restrict__ K,
             const u16* __restrict__ Vt, u16* __restrict__ ctxA,
             u16* __restrict__ ctxB)
{
    __shared__ float Sb[16 * 16 * 32];   // [h][q][k]
    __shared__ u16   Pb[16 * 16 * 32];   // [h][q][k]

    const int t     = threadIdx.x;
    const int w     = t >> 6, lane = t & 63;
    const int quad  = lane >> 4, lm = lane & 15;
    const int khalf = blockIdx.x & 1;
    const int qt    = (blockIdx.x >> 1) & 127;
    const int b     = blockIdx.x >> 8;
    const int q0    = qt * 16;

    const size_t qbase = ((size_t)b * S_LEN + q0) * E_DIM;
    const size_t kmat  = (size_t)b * S_LEN * E_DIM;
    const size_t vtb   = (size_t)b * E_DIM * S_LEN;

    // Q fragments (persistent): A[m=lm(q)][k = quad*8+j]
    bf16x8 qf[4][2];
#pragma unroll
    for (int h2 = 0; h2 < 4; ++h2)
#pragma unroll
        for (int hf = 0; hf < 2; ++hf)
            qf[h2][hf] = *(const bf16x8*)(Q + qbase + (size_t)lm * E_DIM
                                          + (w * 4 + h2) * 64 + hf * 32 + quad * 8);

    f32x4 acc[4][4] = {};   // [h2][dtile]

    const int kbeg = khalf * (S_LEN / 2);

    for (int c = 0; c < (S_LEN / 2) / 32; ++c) {
        const int k0 = kbeg + c * 32;

        // ---- QK^T: scores for this wave's 4 heads ----
#pragma unroll
        for (int h2 = 0; h2 < 4; ++h2) {
            const int h = w * 4 + h2;
#pragma unroll
            for (int kt2 = 0; kt2 < 2; ++kt2) {
                f32x4 sf = {};
#pragma unroll
                for (int hf = 0; hf < 2; ++hf) {
                    bf16x8 kf = *(const bf16x8*)(K + kmat
                                 + (size_t)(k0 + kt2 * 16 + lm) * E_DIM
                                 + h * 64 + hf * 32 + quad * 8);
                    sf = __builtin_amdgcn_mfma_f32_16x16x32_bf16(qf[h2][hf], kf, sf, 0, 0, 0);
                }
                // D: row(q) = quad*4+rg, col(key) = lm
#pragma unroll
                for (int rg = 0; rg < 4; ++rg)
                    Sb[h * 512 + (quad * 4 + rg) * 32 + kt2 * 16 + lm] = sf[rg];
            }
        }
        __syncthreads();

        // ---- wide softmax over heads: 2 (q,k) pairs per thread ----
#pragma unroll
        for (int p = 0; p < 2; ++p) {
            const int idx = p * 256 + t;
            const int qq = idx >> 5, kk = idx & 31;
            float sv[16]; float mx = -1e30f;
#pragma unroll
            for (int h = 0; h < 16; ++h) {
                sv[h] = Sb[h * 512 + qq * 32 + kk];
                mx = fmaxf(mx, sv[h]);
            }
            float sum = 0.f;
#pragma unroll
            for (int h = 0; h < 16; ++h) {
                sv[h] = __expf((sv[h] - mx) * 0.125f);   // 1/sqrt(64) folded in
                sum += sv[h];
            }
            const float inv = 1.f / sum;
#pragma unroll
            for (int h = 0; h < 16; ++h)
                Pb[h * 512 + qq * 32 + kk] = f2bf(sv[h] * inv);
        }
        __syncthreads();

        // ---- PV: ctx[q][d] += P[q,keys] * Vt[d,keys] ----
#pragma unroll
        for (int h2 = 0; h2 < 4; ++h2) {
            const int h = w * 4 + h2;
            bf16x8 pf = *(const bf16x8*)(Pb + h * 512 + lm * 32 + quad * 8);
#pragma unroll
            for (int dt = 0; dt < 4; ++dt) {
                bf16x8 vf = *(const bf16x8*)(Vt + vtb
                             + (size_t)(h * 64 + dt * 16 + lm) * S_LEN
                             + k0 + quad * 8);
                acc[h2][dt] = __builtin_amdgcn_mfma_f32_16x16x32_bf16(pf, vf, acc[h2][dt], 0, 0, 0);
            }
        }
        // next chunk's S writes are safe: softmax reads completed before the
        // barrier above; P reads (this PV) complete before the next barrier.
    }

    __syncthreads();
    // ---- epilogue: stage tile in LDS (reuse Sb) then coalesced store ----
    u16* Ol = (u16*)Sb;     // [16 q][1024 e]
#pragma unroll
    for (int h2 = 0; h2 < 4; ++h2) {
        const int h = w * 4 + h2;
#pragma unroll
        for (int dt = 0; dt < 4; ++dt)
#pragma unroll
            for (int rg = 0; rg < 4; ++rg)
                Ol[(quad * 4 + rg) * 1024 + h * 64 + dt * 16 + lm] = f2bf(acc[h2][dt][rg]);
    }
    __syncthreads();
    u16* dst = khalf ? ctxB : ctxA;
#pragma unroll
    for (int i = 0; i < 8; ++i) {
        const int unit = i * 256 + t;
        const int r = unit >> 7, cu = unit & 127;
        *(bf16x8*)(dst + ((size_t)b * S_LEN + q0 + r) * E_DIM + cu * 8) =
            *(const bf16x8*)(Ol + r * 1024 + cu * 8);
    }
}

// ---------------------------------------------------------------------------
extern "C" void kernel_launch(void* const* d_in, const int* in_sizes, int n_in,
                              void* d_out, int out_size, void* d_ws, size_t ws_size,
                              hipStream_t stream)
{
    const float* x  = (const float*)d_in[0];
    const float* Wq = (const float*)d_in[1];
    const float* bq = (const float*)d_in[2];
    const float* Wk = (const float*)d_in[3];
    const float* bk = (const float*)d_in[4];
    const float* Wv = (const float*)d_in[5];
    const float* bv = (const float*)d_in[6];
    const float* Wo = (const float*)d_in[7];
    const float* bo = (const float*)d_in[8];
    float* out = (float*)d_out;

    // bf16 workspace layout (u16 elements), 64 MB total:
    const size_t MAT = (size_t)M_ROWS * E_DIM;   // 4M elems
    const size_t WSZ = (size_t)E_DIM * E_DIM;    // 1M elems
    u16* xb   = (u16*)d_ws;          // 8 MB
    u16* Wqb  = xb   + MAT;          // 2 MB
    u16* Wkb  = Wqb  + WSZ;
    u16* Wvb  = Wkb  + WSZ;
    u16* Wob  = Wvb  + WSZ;
    u16* Qb   = Wob  + WSZ;          // 8 MB
    u16* Kb   = Qb   + MAT;
    u16* Vb   = Kb   + MAT;
    u16* Vtb  = Vb   + MAT;
    u16* ctxA = Vtb  + MAT;
    u16* ctxB = ctxA + MAT;

    // 1) convert inputs to bf16
    cvt_bf16<<<(int)(MAT / 1024), 256, 0, stream>>>(x,  xb,  (int)MAT);
    cvt_bf16<<<(int)(WSZ / 1024), 256, 0, stream>>>(Wq, Wqb, (int)WSZ);
    cvt_bf16<<<(int)(WSZ / 1024), 256, 0, stream>>>(Wk, Wkb, (int)WSZ);
    cvt_bf16<<<(int)(WSZ / 1024), 256, 0, stream>>>(Wv, Wvb, (int)WSZ);
    cvt_bf16<<<(int)(WSZ / 1024), 256, 0, stream>>>(Wo, Wob, (int)WSZ);

    // 2) Q/K/V projections (bf16 out)
    dim3 ggrid(M_ROWS / 128, E_DIM / 128);   // 32 x 8
    gemm_bt<true><<<ggrid, 256, 0, stream>>>(xb, Wqb, bq, Qb, M_ROWS, E_DIM, E_DIM);
    gemm_bt<true><<<ggrid, 256, 0, stream>>>(xb, Wkb, bk, Kb, M_ROWS, E_DIM, E_DIM);
    gemm_bt<true><<<ggrid, 256, 0, stream>>>(xb, Wvb, bv, Vb, M_ROWS, E_DIM, E_DIM);

    // 3) V transpose -> Vt [b][e][s]
    transpose_v<<<BATCH * 128, 256, 0, stream>>>(Vb, Vtb);

    // 4) fused MFMA attention (softmax over heads), KSPLIT=2
    attn_v3<<<BATCH * 128 * 2, 256, 0, stream>>>(Qb, Kb, Vtb, ctxA, ctxB);

    // 5) combine k-halves (reuse xb as combined ctx)
    combine_ctx<<<(int)(MAT / 1024), 256, 0, stream>>>(ctxA, ctxB, xb, (int)MAT);

    // 6) output projection (fp32 out)
    gemm_bt<false><<<ggrid, 256, 0, stream>>>(xb, Wob, bo, out, M_ROWS, E_DIM, E_DIM);
}